// Round 5
// baseline (19626.627 us; speedup 1.0000x reference)
//
#include <hip/hip_runtime.h>
#include <math.h>

#define TT 64
#define BB 256
#define OBS 512
#define ACTN 16
#define EMB 512
#define HID 1024
#define NCAT 32
#define NCLS 32
#define ZD 1024
#define G3 3072

typedef short s16x8 __attribute__((ext_vector_type(8)));
typedef float floatx4 __attribute__((ext_vector_type(4)));
typedef unsigned long long u64;

__device__ __forceinline__ unsigned short f2bf(float f) {
    unsigned int u = __float_as_uint(f);
    unsigned int r = (u + 0x7fffu + ((u >> 16) & 1u)) >> 16;
    return (unsigned short)r;
}
__device__ __forceinline__ float bf2f(unsigned short h) {
    return __uint_as_float(((unsigned int)h) << 16);
}
__device__ __forceinline__ float elu1(float v) {
    return v > 0.f ? v : (expf(v) - 1.f);
}
__device__ __forceinline__ float sigm(float v) {
    return 1.f / (1.f + expf(-v));
}

// ---------------------------------------------------------------- fast device barrier
// arr: one 64B slot per block (no RMW contention); go: broadcast epoch.
__device__ __forceinline__ void dev_barrier(int* arr, int* go, int blk, int nblk, int epoch) {
    __syncthreads();
    if (threadIdx.x == 0) {
        __threadfence();   // release: make prior global writes visible at agent scope
        __hip_atomic_store(&arr[blk * 16], epoch, __ATOMIC_RELEASE, __HIP_MEMORY_SCOPE_AGENT);
    }
    if (blk == 0) {
        for (int i = threadIdx.x; i < nblk; i += blockDim.x) {
            while (__hip_atomic_load(&arr[i * 16], __ATOMIC_ACQUIRE,
                                     __HIP_MEMORY_SCOPE_AGENT) < epoch)
                __builtin_amdgcn_s_sleep(1);
        }
        __syncthreads();
        if (threadIdx.x == 0)
            __hip_atomic_store(go, epoch, __ATOMIC_RELEASE, __HIP_MEMORY_SCOPE_AGENT);
    } else {
        if (threadIdx.x == 0) {
            while (__hip_atomic_load(go, __ATOMIC_ACQUIRE,
                                     __HIP_MEMORY_SCOPE_AGENT) < epoch)
                __builtin_amdgcn_s_sleep(1);
        }
    }
    if (threadIdx.x == 0) __threadfence();   // acquire: invalidate stale cached lines
    __syncthreads();
}

// ---------------------------------------------------------------- one-hot -> index
__global__ void k_idx(const float* __restrict__ obs, const float* __restrict__ act,
                      int* __restrict__ obs_idx, int* __restrict__ act_idx) {
    int wave = (blockIdx.x * blockDim.x + threadIdx.x) >> 6;
    int lane = threadIdx.x & 63;
    if (wave >= TT * BB) return;
    const float* o = obs + (size_t)wave * OBS;
    int found = -1;
    #pragma unroll
    for (int j = 0; j < 8; ++j) {
        float v = o[lane + 64 * j];
        if (v > 0.5f) found = lane + 64 * j;
    }
    unsigned long long m = __ballot(found >= 0);
    int src = __ffsll(m) - 1;
    int oidx = __shfl(found, src);
    int af = -1;
    if (lane < ACTN) {
        float v = act[(size_t)wave * ACTN + lane];
        if (v > 0.5f) af = lane;
    }
    unsigned long long m2 = __ballot(af >= 0);
    int src2 = __ffsll(m2) - 1;
    int aidx = __shfl(af, src2);
    if (lane == 0) { obs_idx[wave] = oidx; act_idx[wave] = aidx; }
}

// ---------------------------------------------------------------- transpose fp32 -> bf16
__global__ void k_transp(const float* __restrict__ in, int instride,
                         unsigned short* __restrict__ out, int ldo, int ko) {
    __shared__ float t[32][33];
    int c0 = blockIdx.x * 32, r0 = blockIdx.y * 32;
    int tx = threadIdx.x, ty = threadIdx.y;
    #pragma unroll
    for (int i = 0; i < 4; ++i)
        t[ty + 8 * i][tx] = in[(size_t)(r0 + ty + 8 * i) * instride + c0 + tx];
    __syncthreads();
    #pragma unroll
    for (int i = 0; i < 4; ++i)
        out[(size_t)(c0 + ty + 8 * i) * ldo + ko + r0 + tx] = f2bf(t[tx][ty + 8 * i]);
}

// ---------------------------------------------------------------- fp32 -> bf16 cast
__global__ void k_cast(const float* __restrict__ in, unsigned short* __restrict__ out, int n) {
    int i = blockIdx.x * 256 + threadIdx.x;
    if (i < n) out[i] = f2bf(in[i]);
}

__global__ void k_pack_bias(const float* bd1, const float* br1, const float* bc1,
                            float* __restrict__ out) {
    int i = threadIdx.x;
    if (i < 64) out[i] = bd1[i];
    else if (i < 128) out[i] = br1[i - 64];
    else out[i] = bc1[i - 128];
}

__global__ void k_e1(const int* __restrict__ obs_idx, const float* __restrict__ We1,
                     const float* __restrict__ be1, unsigned short* __restrict__ e1) {
    int g = blockIdx.x * 256 + threadIdx.x;
    int s = g >> 6, k = g & 63;
    float v = We1[obs_idx[s] * 64 + k] + be1[k];
    e1[g] = f2bf(elu1(v));
}

// ---------------------------------------------------------------- generic MFMA GEMM (batched)
struct MJob {
    const unsigned short* X; int ldx;
    const unsigned short* WT;
    const float* bias;
    const unsigned short* addb;
    void* out; int ldo;
    int N, K, flags;              // 1=elu, 2=bf16 out, 4=addb
};

__global__ __launch_bounds__(256) void mfma_gemm(MJob j) {
    __shared__ unsigned short Xs[64][40];
    __shared__ unsigned short Ns[64][40];
    int tid = threadIdx.x;
    int m0 = blockIdx.y * 64, n0 = blockIdx.x * 64;
    int r = tid >> 2, p = (tid & 3) * 8;
    const unsigned short* xg = j.X + (size_t)(m0 + r) * j.ldx + p;
    const unsigned short* wg = j.WT + (size_t)(n0 + r) * j.K + p;
    int lane = tid & 63, wv = tid >> 6;
    int wm = (wv & 1) * 32, wn = (wv >> 1) * 32;
    int mi = lane & 15, q = lane >> 4;
    floatx4 acc00 = {0.f, 0.f, 0.f, 0.f};
    floatx4 acc01 = acc00, acc10 = acc00, acc11 = acc00;
    for (int kt = 0; kt < j.K; kt += 32) {
        *(float4*)&Xs[r][p] = *(const float4*)(xg + kt);
        *(float4*)&Ns[r][p] = *(const float4*)(wg + kt);
        __syncthreads();
        s16x8 a0 = *(const s16x8*)&Xs[wm + mi][q * 8];
        s16x8 a1 = *(const s16x8*)&Xs[wm + 16 + mi][q * 8];
        s16x8 b0 = *(const s16x8*)&Ns[wn + mi][q * 8];
        s16x8 b1 = *(const s16x8*)&Ns[wn + 16 + mi][q * 8];
        acc00 = __builtin_amdgcn_mfma_f32_16x16x32_bf16(a0, b0, acc00, 0, 0, 0);
        acc01 = __builtin_amdgcn_mfma_f32_16x16x32_bf16(a0, b1, acc01, 0, 0, 0);
        acc10 = __builtin_amdgcn_mfma_f32_16x16x32_bf16(a1, b0, acc10, 0, 0, 0);
        acc11 = __builtin_amdgcn_mfma_f32_16x16x32_bf16(a1, b1, acc11, 0, 0, 0);
        __syncthreads();
    }
    #pragma unroll
    for (int i = 0; i < 2; ++i) {
        #pragma unroll
        for (int jj = 0; jj < 2; ++jj) {
            floatx4 a = (i == 0) ? ((jj == 0) ? acc00 : acc01)
                                 : ((jj == 0) ? acc10 : acc11);
            int col = n0 + wn + jj * 16 + mi;
            float badd = j.bias ? j.bias[col] : 0.f;
            #pragma unroll
            for (int rg = 0; rg < 4; ++rg) {
                int row = m0 + wm + i * 16 + q * 4 + rg;
                float v = a[rg] + badd;
                if (j.flags & 4) v += bf2f(j.addb[(size_t)row * j.N + col]);
                if (j.flags & 1) v = elu1(v);
                if (j.flags & 2)
                    ((unsigned short*)j.out)[(size_t)row * j.ldo + col] = f2bf(v);
                else
                    ((float*)j.out)[(size_t)row * j.ldo + col] = v;
            }
        }
    }
}

// ---------------------------------------------------------------- 64x64 K=1024 GEMM helper
__device__ __forceinline__ void gemm64(const unsigned short* __restrict__ A, int lda,
                                       const unsigned short* __restrict__ B,
                                       unsigned short Xs[64][136], unsigned short Ns[64][136],
                                       int tid, int wm, int wn, int mi, int q,
                                       floatx4 acc[2][2]) {
    int r = tid >> 2, pp = (tid & 3) * 8;
    const unsigned short* xg = A + (size_t)r * lda + pp;
    const unsigned short* wg = B + (size_t)r * 1024 + pp;
    float4 xv[4], wvv[4];
    #pragma unroll
    for (int c = 0; c < 4; ++c) {
        xv[c] = *(const float4*)(xg + 32 * c);
        wvv[c] = *(const float4*)(wg + 32 * c);
    }
    for (int rd = 0; rd < 8; ++rd) {
        __syncthreads();
        #pragma unroll
        for (int c = 0; c < 4; ++c) {
            *(float4*)&Xs[r][pp + 32 * c] = xv[c];
            *(float4*)&Ns[r][pp + 32 * c] = wvv[c];
        }
        __syncthreads();
        if (rd < 7) {
            int kt = (rd + 1) * 128;
            #pragma unroll
            for (int c = 0; c < 4; ++c) {
                xv[c] = *(const float4*)(xg + kt + 32 * c);
                wvv[c] = *(const float4*)(wg + kt + 32 * c);
            }
        }
        #pragma unroll
        for (int c = 0; c < 4; ++c) {
            s16x8 a0 = *(const s16x8*)&Xs[wm + mi][c * 32 + q * 8];
            s16x8 a1 = *(const s16x8*)&Xs[wm + 16 + mi][c * 32 + q * 8];
            s16x8 b0 = *(const s16x8*)&Ns[wn + mi][c * 32 + q * 8];
            s16x8 b1 = *(const s16x8*)&Ns[wn + 16 + mi][c * 32 + q * 8];
            acc[0][0] = __builtin_amdgcn_mfma_f32_16x16x32_bf16(a0, b0, acc[0][0], 0, 0, 0);
            acc[0][1] = __builtin_amdgcn_mfma_f32_16x16x32_bf16(a0, b1, acc[0][1], 0, 0, 0);
            acc[1][0] = __builtin_amdgcn_mfma_f32_16x16x32_bf16(a1, b0, acc[1][0], 0, 0, 0);
            acc[1][1] = __builtin_amdgcn_mfma_f32_16x16x32_bf16(a1, b1, acc[1][1], 0, 0, 0);
        }
    }
}

// ---------------------------------------------------------------- persistent scan
struct ScanP {
    const unsigned short *WhT, *Wq1aT, *Wq2T, *Wp1T, *WizBF, *Eq;
    const float *Wi, *bi, *bh, *bq2, *bp1, *gum;
    const int *act_idx;
    unsigned short *XZ, *post1, *postL, *pri1;
    float *ghbuf, *h_st;
    int *zidx;
    int *bar;     // [256*16] arrival slots + [1] go flag after them
};

__global__ __launch_bounds__(256, 1) void k_scan(ScanP P) {
    __shared__ unsigned short Xs[64][136];
    __shared__ unsigned short Ns[64][136];
    __shared__ int zs[33];
    int tid = threadIdx.x;
    int blk = blockIdx.x;
    int lane = tid & 63, wv = tid >> 6;
    int wm = (wv & 1) * 32, wn = (wv >> 1) * 32;
    int mi = lane & 15, q = lane >> 4;
    int* arr = P.bar;
    int* go  = P.bar + 256 * 16;
    int ep = 0;

    for (int t = 1; t <= TT; ++t) {
        // ---------- S3: GRU + z-gather (block = batch row)
        {
            int b = blk;
            if (tid < 32) zs[tid] = (t > 1) ? (tid * 32 + P.zidx[b * 32 + tid]) : 0;
            if (tid == 0) zs[32] = 1024 + P.act_idx[(t - 1) * 256 + b];
            __syncthreads();
            int j0 = tid * 4;
            float g[3][4];
            #pragma unroll
            for (int gi = 0; gi < 3; ++gi) {
                int col = gi * 1024 + j0;
                float4 bi4 = *(const float4*)(P.bi + col);
                float4 wa  = *(const float4*)(P.Wi + (size_t)zs[32] * G3 + col);
                g[gi][0] = bi4.x + wa.x; g[gi][1] = bi4.y + wa.y;
                g[gi][2] = bi4.z + wa.z; g[gi][3] = bi4.w + wa.w;
            }
            if (t > 1) {
                #pragma unroll 4
                for (int c = 0; c < 32; ++c) {
                    const unsigned short* wr = P.WizBF + (size_t)zs[c] * G3 + j0;
                    #pragma unroll
                    for (int gi = 0; gi < 3; ++gi) {
                        u64 w = *(const u64*)(wr + gi * 1024);
                        g[gi][0] += bf2f((unsigned short)w);
                        g[gi][1] += bf2f((unsigned short)(w >> 16));
                        g[gi][2] += bf2f((unsigned short)(w >> 32));
                        g[gi][3] += bf2f((unsigned short)(w >> 48));
                    }
                }
            }
            const float* ghs = (t == 1) ? P.bh : (P.ghbuf + (size_t)b * G3);
            float4 gr = *(const float4*)(ghs + j0);
            float4 gu = *(const float4*)(ghs + 1024 + j0);
            float4 gn = *(const float4*)(ghs + 2048 + j0);
            float4 hp = *(const float4*)(P.h_st + (size_t)b * HID + j0);
            float grv[4] = {gr.x, gr.y, gr.z, gr.w};
            float guv[4] = {gu.x, gu.y, gu.z, gu.w};
            float gnv[4] = {gn.x, gn.y, gn.z, gn.w};
            float hpv[4] = {hp.x, hp.y, hp.z, hp.w};
            float ho[4];
            #pragma unroll
            for (int k = 0; k < 4; ++k) {
                float rr = sigm(g[0][k] + grv[k]);
                float uu = sigm(g[1][k] + guv[k]);
                float nn = tanhf(g[2][k] + rr * gnv[k]);
                ho[k] = (1.f - uu) * nn + uu * hpv[k];
            }
            *(float4*)(P.h_st + (size_t)b * HID + j0) = make_float4(ho[0], ho[1], ho[2], ho[3]);
            u64 pk = (u64)f2bf(ho[0]) | ((u64)f2bf(ho[1]) << 16) |
                     ((u64)f2bf(ho[2]) << 32) | ((u64)f2bf(ho[3]) << 48);
            __builtin_nontemporal_store(pk, (u64*)(P.XZ + ((size_t)t * 256 + b) * 2048 + j0));
        }
        dev_barrier(arr, go, blk, 256, ++ep);

        // ---------- S1: post1_t (blk 0..63)  |  gh_{t+1} (blk 64..255)
        const unsigned short* XZt = P.XZ + (size_t)t * 256 * 2048;
        if (blk < 64) {
            int m0 = (blk & 3) * 64, n0 = (blk >> 2) * 64;
            floatx4 z4 = {0.f, 0.f, 0.f, 0.f};
            floatx4 acc[2][2] = {{z4, z4}, {z4, z4}};
            gemm64(XZt + (size_t)m0 * 2048, 2048, P.Wq1aT + (size_t)n0 * 1024,
                   Xs, Ns, tid, wm, wn, mi, q, acc);
            const unsigned short* Eqt = P.Eq + (size_t)(t - 1) * 262144;
            #pragma unroll
            for (int i = 0; i < 2; ++i)
                #pragma unroll
                for (int jj = 0; jj < 2; ++jj) {
                    int col = n0 + wn + jj * 16 + mi;
                    #pragma unroll
                    for (int rg = 0; rg < 4; ++rg) {
                        int row = m0 + wm + i * 16 + q * 4 + rg;
                        unsigned short eb = __builtin_nontemporal_load(
                            Eqt + (size_t)row * 1024 + col);
                        float v = acc[i][jj][rg] + bf2f(eb);
                        P.post1[(size_t)row * 1024 + col] = f2bf(elu1(v));
                    }
                }
        } else if (t < TT) {
            int local = blk - 64;
            int m0 = (local & 3) * 64, n0 = (local >> 2) * 64;
            floatx4 z4 = {0.f, 0.f, 0.f, 0.f};
            floatx4 acc[2][2] = {{z4, z4}, {z4, z4}};
            gemm64(XZt + (size_t)m0 * 2048, 2048, P.WhT + (size_t)n0 * 1024,
                   Xs, Ns, tid, wm, wn, mi, q, acc);
            #pragma unroll
            for (int i = 0; i < 2; ++i)
                #pragma unroll
                for (int jj = 0; jj < 2; ++jj) {
                    int col = n0 + wn + jj * 16 + mi;
                    float bb = P.bh[col];
                    #pragma unroll
                    for (int rg = 0; rg < 4; ++rg) {
                        int row = m0 + wm + i * 16 + q * 4 + rg;
                        P.ghbuf[(size_t)row * G3 + col] = acc[i][jj][rg] + bb;
                    }
                }
        }
        dev_barrier(arr, go, blk, 256, ++ep);

        // ---------- S2: postL_t + sample (blk 0..63)  |  prior1_t (blk 64..127)
        if (blk < 64) {
            int m0 = (blk & 3) * 64, n0 = (blk >> 2) * 64;
            floatx4 z4 = {0.f, 0.f, 0.f, 0.f};
            floatx4 acc[2][2] = {{z4, z4}, {z4, z4}};
            gemm64(P.post1 + (size_t)m0 * 1024, 1024, P.Wq2T + (size_t)n0 * 1024,
                   Xs, Ns, tid, wm, wn, mi, q, acc);
            unsigned short* pLt = P.postL + (size_t)(t - 1) * 262144;
            const float* gum_t = P.gum + (size_t)(t - 1) * 262144;
            unsigned short* XZtw = P.XZ + (size_t)t * 256 * 2048;
            float bA = P.bq2[n0 + wn + mi];
            float bB = P.bq2[n0 + wn + 16 + mi];
            #pragma unroll
            for (int i = 0; i < 2; ++i)
                #pragma unroll
                for (int jj = 0; jj < 2; ++jj) {
                    int col = n0 + wn + jj * 16 + mi;
                    float bb = jj ? bB : bA;
                    #pragma unroll
                    for (int rg = 0; rg < 4; ++rg) {
                        acc[i][jj][rg] += bb;
                        int row = m0 + wm + i * 16 + q * 4 + rg;
                        __builtin_nontemporal_store(f2bf(acc[i][jj][rg]),
                                                    pLt + (size_t)row * 1024 + col);
                    }
                }
            int cat = (n0 + wn) >> 5;
            #pragma unroll
            for (int i = 0; i < 2; ++i) {
                #pragma unroll
                for (int rg = 0; rg < 4; ++rg) {
                    int row = m0 + wm + i * 16 + q * 4 + rg;
                    const float* gr = gum_t + (size_t)row * 1024 + cat * 32;
                    float v0 = acc[i][0][rg] + __builtin_nontemporal_load(gr + mi);
                    float v1 = acc[i][1][rg] + __builtin_nontemporal_load(gr + 16 + mi);
                    float bv; int cls;
                    if (v1 > v0) { bv = v1; cls = 16 + mi; } else { bv = v0; cls = mi; }
                    #pragma unroll
                    for (int off = 1; off < 16; off <<= 1) {
                        float ov = __shfl_xor(bv, off);
                        int oc = __shfl_xor(cls, off);
                        if (ov > bv || (ov == bv && oc < cls)) { bv = ov; cls = oc; }
                    }
                    unsigned short* zo = XZtw + (size_t)row * 2048 + 1024 + cat * 32;
                    __builtin_nontemporal_store((unsigned short)((mi == cls) ? 0x3F80 : 0),
                                                zo + mi);
                    __builtin_nontemporal_store((unsigned short)((16 + mi == cls) ? 0x3F80 : 0),
                                                zo + 16 + mi);
                    if (mi == 0) P.zidx[row * 32 + cat] = cls;
                }
            }
        } else if (blk < 128) {
            int local = blk - 64;
            int m0 = (local & 3) * 64, n0 = (local >> 2) * 64;
            floatx4 z4 = {0.f, 0.f, 0.f, 0.f};
            floatx4 acc[2][2] = {{z4, z4}, {z4, z4}};
            gemm64(XZt + (size_t)m0 * 2048, 2048, P.Wp1T + (size_t)n0 * 1024,
                   Xs, Ns, tid, wm, wn, mi, q, acc);
            #pragma unroll
            for (int i = 0; i < 2; ++i)
                #pragma unroll
                for (int jj = 0; jj < 2; ++jj) {
                    int col = n0 + wn + jj * 16 + mi;
                    float bb = P.bp1[col];
                    #pragma unroll
                    for (int rg = 0; rg < 4; ++rg) {
                        int row = m0 + wm + i * 16 + q * 4 + rg;
                        float v = elu1(acc[i][jj][rg] + bb);
                        __builtin_nontemporal_store(f2bf(v),
                            P.pri1 + ((size_t)(t - 1) * 256 + row) * 1024 + col);
                    }
                }
        }
        dev_barrier(arr, go, blk, 256, ++ep);
    }
}

// ---------------------------------------------------------------- KL (deferred)
__global__ void k_kl(const unsigned short* __restrict__ postL,
                     const unsigned short* __restrict__ priorL,
                     float* __restrict__ kl_acc) {
    int g = blockIdx.x * 256 + threadIdx.x;
    int sidx = g >> 5, cat = g & 31;
    const unsigned short* ql = postL + (size_t)sidx * ZD + cat * NCLS;
    const unsigned short* pl = priorL + (size_t)sidx * ZD + cat * NCLS;
    float vq[32], vp[32];
    float mq = -1e30f, mp = -1e30f;
    #pragma unroll
    for (int i = 0; i < NCLS; ++i) {
        vq[i] = bf2f(ql[i]); vp[i] = bf2f(pl[i]);
        mq = fmaxf(mq, vq[i]); mp = fmaxf(mp, vp[i]);
    }
    float sq = 0.f, sp = 0.f;
    #pragma unroll
    for (int i = 0; i < NCLS; ++i) { sq += expf(vq[i] - mq); sp += expf(vp[i] - mp); }
    float lseq = mq + logf(sq), lsep = mp + logf(sp);
    float kl = 0.f;
    #pragma unroll
    for (int i = 0; i < NCLS; ++i) {
        float lpq = vq[i] - lseq;
        kl += expf(lpq) * (lpq - (vp[i] - lsep));
    }
    __shared__ float red[256];
    red[threadIdx.x] = kl;
    __syncthreads();
    for (int s = 128; s > 0; s >>= 1) {
        if ((int)threadIdx.x < s) red[threadIdx.x] += red[threadIdx.x + s];
        __syncthreads();
    }
    if (threadIdx.x == 0) atomicAdd(&kl_acc[sidx >> 8], red[0]);
}

// ---------------------------------------------------------------- CE over 512 logits
__global__ void k_ce(const unsigned short* __restrict__ logits,
                     const int* __restrict__ obs_idx, float* __restrict__ ce_acc) {
    int s = (blockIdx.x * 256 + threadIdx.x) >> 6;
    int lane = threadIdx.x & 63;
    union { float4 f4; unsigned short u[8]; } raw;
    raw.f4 = *(const float4*)(logits + (size_t)s * OBS + lane * 8);
    float v[8];
    float m = -1e30f;
    #pragma unroll
    for (int i = 0; i < 8; ++i) { v[i] = bf2f(raw.u[i]); m = fmaxf(m, v[i]); }
    #pragma unroll
    for (int off = 32; off > 0; off >>= 1) m = fmaxf(m, __shfl_xor(m, off));
    float sum = 0.f;
    #pragma unroll
    for (int i = 0; i < 8; ++i) sum += expf(v[i] - m);
    #pragma unroll
    for (int off = 32; off > 0; off >>= 1) sum += __shfl_xor(sum, off);
    float lse = m + logf(sum);
    int tgt = obs_idx[s];
    float tv = 0.f;
    #pragma unroll
    for (int i = 0; i < 8; ++i) if (lane * 8 + i == tgt) tv = v[i];
    #pragma unroll
    for (int off = 32; off > 0; off >>= 1) tv += __shfl_xor(tv, off);
    if (lane == 0) atomicAdd(&ce_acc[s >> 8], lse - tv);
}

// ---------------------------------------------------------------- reward / continue heads
__global__ void k_heads(const unsigned short* __restrict__ dec1,
                        const float* __restrict__ Wr2, const float* __restrict__ br2,
                        const float* __restrict__ Wc2, const float* __restrict__ bc2,
                        const float* __restrict__ rew, const float* __restrict__ done,
                        float* __restrict__ mse_acc, float* __restrict__ bce_acc) {
    int s = (blockIdx.x * 256 + threadIdx.x) >> 6;
    int lane = threadIdx.x & 63;
    float vr = bf2f(dec1[(size_t)s * 192 + 64 + lane]) * Wr2[lane];
    float vc = bf2f(dec1[(size_t)s * 192 + 128 + lane]) * Wc2[lane];
    #pragma unroll
    for (int off = 32; off > 0; off >>= 1) {
        vr += __shfl_xor(vr, off);
        vc += __shfl_xor(vc, off);
    }
    if (lane == 0) {
        float r_pred = vr + br2[0], c_pred = vc + bc2[0];
        float rt = rew[s];
        float sgn = (rt > 0.f) ? 1.f : ((rt < 0.f) ? -1.f : 0.f);
        float r_tgt = sgn * log1pf(fabsf(rt));
        float d = r_pred - r_tgt;
        float ct = 1.f - done[s];
        float bce = fmaxf(c_pred, 0.f) - c_pred * ct + log1pf(expf(-fabsf(c_pred)));
        atomicAdd(&mse_acc[s >> 8], d * d);
        atomicAdd(&bce_acc[s >> 8], bce);
    }
}

// ---------------------------------------------------------------- final reduce
__global__ void k_final(const float* __restrict__ ce_acc, const float* __restrict__ mse_acc,
                        const float* __restrict__ bce_acc, const float* __restrict__ kl_acc,
                        float* __restrict__ out) {
    int t = threadIdx.x;
    float ce = ce_acc[t] * (1.f / 256.f);
    float ms = mse_acc[t] * (1.f / 256.f);
    float bc = bce_acc[t] * (1.f / 256.f);
    float ka = kl_acc[t] * (1.f / 256.f);
    float kt = fmaxf(ka, 1.f);
    #pragma unroll
    for (int off = 32; off > 0; off >>= 1) {
        ce += __shfl_down(ce, off);
        ms += __shfl_down(ms, off);
        bc += __shfl_down(bc, off);
        kt += __shfl_down(kt, off);
    }
    if (t == 0) {
        ce *= (1.f / 64.f); ms *= (1.f / 64.f); bc *= (1.f / 64.f); kt *= (1.f / 64.f);
        out[0] = ce + ms + bc + kt;
        out[1] = ce; out[2] = ms; out[3] = bc; out[4] = kt;
    }
}

// ----------------------------------------------------------------------------------
extern "C" void kernel_launch(void* const* d_in, const int* in_sizes, int n_in,
                              void* d_out, int out_size, void* d_ws, size_t ws_size,
                              hipStream_t stream) {
    const float* obs  = (const float*)d_in[0];
    const float* act  = (const float*)d_in[1];
    const float* rew  = (const float*)d_in[2];
    const float* done = (const float*)d_in[3];
    const float* gum  = (const float*)d_in[4];
    const float* We1  = (const float*)d_in[5];
    const float* be1  = (const float*)d_in[6];
    const float* We2  = (const float*)d_in[7];
    const float* be2  = (const float*)d_in[8];
    const float* Wi   = (const float*)d_in[9];
    const float* Wh   = (const float*)d_in[10];
    const float* bi   = (const float*)d_in[11];
    const float* bh   = (const float*)d_in[12];
    const float* Wp1  = (const float*)d_in[13];
    const float* bp1  = (const float*)d_in[14];
    const float* Wp2  = (const float*)d_in[15];
    const float* bp2  = (const float*)d_in[16];
    const float* Wq1  = (const float*)d_in[17];
    const float* bq1  = (const float*)d_in[18];
    const float* Wq2  = (const float*)d_in[19];
    const float* bq2  = (const float*)d_in[20];
    const float* Wd1  = (const float*)d_in[21];
    const float* bd1  = (const float*)d_in[22];
    const float* Wd2  = (const float*)d_in[23];
    const float* bd2  = (const float*)d_in[24];
    const float* Wr1  = (const float*)d_in[25];
    const float* br1  = (const float*)d_in[26];
    const float* Wr2  = (const float*)d_in[27];
    const float* br2  = (const float*)d_in[28];
    const float* Wc1  = (const float*)d_in[29];
    const float* bc1  = (const float*)d_in[30];
    const float* Wc2  = (const float*)d_in[31];
    const float* bc2  = (const float*)d_in[32];

    char* base = (char*)d_ws;
    size_t off = 0;
    auto alloc = [&](size_t bytes) -> char* {
        char* p = base + off;
        off += (bytes + 255) & ~(size_t)255;
        return p;
    };
    unsigned short* WhT   = (unsigned short*)alloc(3072u * 1024 * 2);
    unsigned short* WizBF = (unsigned short*)alloc(1024u * 3072 * 2);
    unsigned short* Wq1aT = (unsigned short*)alloc(1024u * 1024 * 2);
    unsigned short* Wq1bT = (unsigned short*)alloc(1024u * 512 * 2);
    unsigned short* Wq2T  = (unsigned short*)alloc(1024u * 1024 * 2);
    unsigned short* Wp1T  = (unsigned short*)alloc(1024u * 1024 * 2);
    unsigned short* Wp2T  = (unsigned short*)alloc(1024u * 1024 * 2);
    unsigned short* WdrcT = (unsigned short*)alloc(192u * 2048 * 2);
    unsigned short* Wd2T  = (unsigned short*)alloc(512u * 64 * 2);
    unsigned short* We2T  = (unsigned short*)alloc(512u * 64 * 2);
    float*          b_drc = (float*)alloc(192 * 4);
    unsigned short* XZ    = (unsigned short*)alloc(65u * 256 * 2048 * 2);   // 68 MB
    float*          h_st  = (float*)alloc(256u * 1024 * 4);
    float*          ghbuf = (float*)alloc(256u * 3072 * 4);
    unsigned short* post1 = (unsigned short*)alloc(256u * 1024 * 2);
    unsigned short* postL = (unsigned short*)alloc(16384u * 1024 * 2);      // 32 MB (reused: logits)
    unsigned short* Eq    = (unsigned short*)alloc(16384u * 1024 * 2);      // 32 MB (reused: priorL)
    unsigned short* pri1  = (unsigned short*)alloc(16384u * 1024 * 2);      // 32 MB
    unsigned short* dec1  = (unsigned short*)alloc(16384u * 192 * 2);
    float*          acc   = (float*)alloc(256 * 4);
    int*            obs_idx = (int*)alloc(16384 * 4);
    int*            act_idx = (int*)alloc(16384 * 4);
    int*            zidx    = (int*)alloc(256 * 32 * 4);
    int*            bar     = (int*)alloc((256 * 16 + 16) * 4);
    unsigned short* embed = pri1;                    // setup-time aliases (pri1 unused then)
    unsigned short* e1    = pri1 + 16384u * 512;

    hipMemsetAsync(h_st, 0, 256u * 1024 * 4, stream);
    hipMemsetAsync(acc, 0, 256 * 4, stream);
    hipMemsetAsync(bar, 0, (256 * 16 + 16) * 4, stream);

    k_idx<<<4096, 256, 0, stream>>>(obs, act, obs_idx, act_idx);

    dim3 tb(32, 8);
    k_transp<<<dim3(96, 32), tb, 0, stream>>>(Wh, 3072, WhT, 1024, 0);
    k_cast<<<(1024 * 3072) / 256, 256, 0, stream>>>(Wi, WizBF, 1024 * 3072);
    k_transp<<<dim3(32, 32), tb, 0, stream>>>(Wq1, 1024, Wq1aT, 1024, 0);
    k_transp<<<dim3(32, 16), tb, 0, stream>>>(Wq1 + 1024u * 1024, 1024, Wq1bT, 512, 0);
    k_transp<<<dim3(32, 32), tb, 0, stream>>>(Wq2, 1024, Wq2T, 1024, 0);
    k_transp<<<dim3(32, 32), tb, 0, stream>>>(Wp1, 1024, Wp1T, 1024, 0);
    k_transp<<<dim3(32, 32), tb, 0, stream>>>(Wp2, 1024, Wp2T, 1024, 0);
    k_transp<<<dim3(2, 64),  tb, 0, stream>>>(Wd1, 64, WdrcT, 2048, 0);
    k_transp<<<dim3(2, 64),  tb, 0, stream>>>(Wr1, 64, WdrcT + 64u * 2048, 2048, 0);
    k_transp<<<dim3(2, 64),  tb, 0, stream>>>(Wc1, 64, WdrcT + 128u * 2048, 2048, 0);
    k_transp<<<dim3(16, 2),  tb, 0, stream>>>(Wd2, 512, Wd2T, 64, 0);
    k_transp<<<dim3(16, 2),  tb, 0, stream>>>(We2, 512, We2T, 64, 0);
    k_pack_bias<<<1, 192, 0, stream>>>(bd1, br1, bc1, b_drc);

    // embed & Eq precompute (all 64 steps)
    k_e1<<<4096, 256, 0, stream>>>(obs_idx, We1, be1, e1);
    {
        MJob m = { e1, 64, We2T, be2, nullptr, embed, 512, 512, 64, 2 };
        mfma_gemm<<<dim3(8, 256), 256, 0, stream>>>(m);
    }
    {
        MJob m = { embed, 512, Wq1bT, bq1, nullptr, Eq, 1024, 1024, 512, 2 };
        mfma_gemm<<<dim3(16, 256), 256, 0, stream>>>(m);
    }

    // persistent scan (cooperative launch for co-residency; custom barrier inside)
    ScanP SP;
    SP.WhT = WhT; SP.Wq1aT = Wq1aT; SP.Wq2T = Wq2T; SP.Wp1T = Wp1T;
    SP.WizBF = WizBF; SP.Eq = Eq;
    SP.Wi = Wi; SP.bi = bi; SP.bh = bh; SP.bq2 = bq2; SP.bp1 = bp1; SP.gum = gum;
    SP.act_idx = act_idx;
    SP.XZ = XZ; SP.post1 = post1; SP.postL = postL; SP.pri1 = pri1;
    SP.ghbuf = ghbuf; SP.h_st = h_st; SP.zidx = zidx; SP.bar = bar;
    void* kargs[] = { (void*)&SP };
    hipLaunchCooperativeKernel((const void*)k_scan, dim3(256), dim3(256), kargs, 0, stream);

    // deferred batched passes
    unsigned short* Hall = XZ + (size_t)256 * 2048;
    {
        MJob m = { pri1, 1024, Wp2T, bp2, nullptr, Eq, 1024, 1024, 1024, 2 };
        mfma_gemm<<<dim3(16, 256), 256, 0, stream>>>(m);
    }
    k_kl<<<2048, 256, 0, stream>>>(postL, Eq, acc + 192);
    {
        MJob m = { Hall, 2048, WdrcT, b_drc, nullptr, dec1, 192, 192, 2048, 1 | 2 };
        mfma_gemm<<<dim3(3, 256), 256, 0, stream>>>(m);
    }
    {
        MJob m = { dec1, 192, Wd2T, bd2, nullptr, postL, 512, 512, 64, 2 };
        mfma_gemm<<<dim3(8, 256), 256, 0, stream>>>(m);
    }
    k_ce<<<4096, 256, 0, stream>>>(postL, obs_idx, acc + 0);
    k_heads<<<4096, 256, 0, stream>>>(dec1, Wr2, br2, Wc2, bc2, rew, done,
                                      acc + 64, acc + 128);
    k_final<<<1, 64, 0, stream>>>(acc + 0, acc + 64, acc + 128, acc + 192, (float*)d_out);
}

// Round 6
// 5118.369 us; speedup vs baseline: 3.8345x; 3.8345x over previous
//
#include <hip/hip_runtime.h>
#include <math.h>

#define TT 64
#define BB 256
#define OBS 512
#define ACTN 16
#define EMB 512
#define HID 1024
#define NCAT 32
#define NCLS 32
#define ZD 1024
#define G3 3072

typedef short s16x8 __attribute__((ext_vector_type(8)));
typedef float floatx4 __attribute__((ext_vector_type(4)));
typedef unsigned long long u64;

// barrier buffer layout (ints)
constexpr int CNT_OFF  = 0;                       // 8 counters
constexpr int GARR_OFF = 16;                      // 256 * 16
constexpr int GGO_OFF  = 16 + 256 * 16;           // 1
constexpr int ARR_OFF  = 8192;                    // 8 * 256 * 16
constexpr int GO_OFF   = ARR_OFF + 8 * 256 * 16;  // 8 * 16
constexpr int BAR_INTS = GO_OFF + 8 * 16 + 16;

__device__ __forceinline__ unsigned short f2bf(float f) {
    unsigned int u = __float_as_uint(f);
    unsigned int r = (u + 0x7fffu + ((u >> 16) & 1u)) >> 16;
    return (unsigned short)r;
}
__device__ __forceinline__ float bf2f(unsigned short h) {
    return __uint_as_float(((unsigned int)h) << 16);
}
__device__ __forceinline__ float elu1(float v) {
    return v > 0.f ? v : (expf(v) - 1.f);
}
__device__ __forceinline__ float sigm(float v) {
    return 1.f / (1.f + expf(-v));
}

// release: drain this wave's memory ops to L2 (no L2 writeback needed intra-XCD)
__device__ __forceinline__ void rel_drain() {
    asm volatile("" ::: "memory");
    asm volatile("s_waitcnt vmcnt(0) lgkmcnt(0)" ::: "memory");
}
// acquire: invalidate vector L1 so fresh L2 data is seen
__device__ __forceinline__ void acq_fence() {
    __builtin_amdgcn_fence(__ATOMIC_ACQUIRE, "agent");
    asm volatile("" ::: "memory");
}

// intra-group (intra-XCD) barrier: per-rank slots + go flag, relaxed atomics only
__device__ __forceinline__ void gbar(int* bar, int grp, int rank, int nb, int ep) {
    rel_drain();
    __syncthreads();
    if (threadIdx.x == 0)
        __hip_atomic_store(&bar[ARR_OFF + (grp * 256 + rank) * 16], ep,
                           __ATOMIC_RELAXED, __HIP_MEMORY_SCOPE_AGENT);
    if (rank == 0) {
        for (int i = threadIdx.x; i < nb; i += 256)
            while (__hip_atomic_load(&bar[ARR_OFF + (grp * 256 + i) * 16],
                                     __ATOMIC_RELAXED, __HIP_MEMORY_SCOPE_AGENT) < ep)
                __builtin_amdgcn_s_sleep(1);
        __syncthreads();
        if (threadIdx.x == 0)
            __hip_atomic_store(&bar[GO_OFF + grp * 16], ep,
                               __ATOMIC_RELAXED, __HIP_MEMORY_SCOPE_AGENT);
    } else if (threadIdx.x == 0) {
        while (__hip_atomic_load(&bar[GO_OFF + grp * 16],
                                 __ATOMIC_RELAXED, __HIP_MEMORY_SCOPE_AGENT) < ep)
            __builtin_amdgcn_s_sleep(1);
    }
    __syncthreads();
    acq_fence();
}

// ---------------------------------------------------------------- one-hot -> index
__global__ void k_idx(const float* __restrict__ obs, const float* __restrict__ act,
                      int* __restrict__ obs_idx, int* __restrict__ act_idx) {
    int wave = (blockIdx.x * blockDim.x + threadIdx.x) >> 6;
    int lane = threadIdx.x & 63;
    if (wave >= TT * BB) return;
    const float* o = obs + (size_t)wave * OBS;
    int found = -1;
    #pragma unroll
    for (int j = 0; j < 8; ++j) {
        float v = o[lane + 64 * j];
        if (v > 0.5f) found = lane + 64 * j;
    }
    unsigned long long m = __ballot(found >= 0);
    int src = __ffsll(m) - 1;
    int oidx = __shfl(found, src);
    int af = -1;
    if (lane < ACTN) {
        float v = act[(size_t)wave * ACTN + lane];
        if (v > 0.5f) af = lane;
    }
    unsigned long long m2 = __ballot(af >= 0);
    int src2 = __ffsll(m2) - 1;
    int aidx = __shfl(af, src2);
    if (lane == 0) { obs_idx[wave] = oidx; act_idx[wave] = aidx; }
}

// ---------------------------------------------------------------- transpose fp32 -> bf16
__global__ void k_transp(const float* __restrict__ in, int instride,
                         unsigned short* __restrict__ out, int ldo, int ko) {
    __shared__ float t[32][33];
    int c0 = blockIdx.x * 32, r0 = blockIdx.y * 32;
    int tx = threadIdx.x, ty = threadIdx.y;
    #pragma unroll
    for (int i = 0; i < 4; ++i)
        t[ty + 8 * i][tx] = in[(size_t)(r0 + ty + 8 * i) * instride + c0 + tx];
    __syncthreads();
    #pragma unroll
    for (int i = 0; i < 4; ++i)
        out[(size_t)(c0 + ty + 8 * i) * ldo + ko + r0 + tx] = f2bf(t[tx][ty + 8 * i]);
}

__global__ void k_cast(const float* __restrict__ in, unsigned short* __restrict__ out, int n) {
    int i = blockIdx.x * 256 + threadIdx.x;
    if (i < n) out[i] = f2bf(in[i]);
}

__global__ void k_pack_bias(const float* bd1, const float* br1, const float* bc1,
                            float* __restrict__ out) {
    int i = threadIdx.x;
    if (i < 64) out[i] = bd1[i];
    else if (i < 128) out[i] = br1[i - 64];
    else out[i] = bc1[i - 128];
}

__global__ void k_e1(const int* __restrict__ obs_idx, const float* __restrict__ We1,
                     const float* __restrict__ be1, unsigned short* __restrict__ e1) {
    int g = blockIdx.x * 256 + threadIdx.x;
    int s = g >> 6, k = g & 63;
    float v = We1[obs_idx[s] * 64 + k] + be1[k];
    e1[g] = f2bf(elu1(v));
}

// ---------------------------------------------------------------- generic MFMA GEMM (batched)
struct MJob {
    const unsigned short* X; int ldx;
    const unsigned short* WT;
    const float* bias;
    const unsigned short* addb;
    void* out; int ldo;
    int N, K, flags;              // 1=elu, 2=bf16 out, 4=addb
};

__global__ __launch_bounds__(256) void mfma_gemm(MJob j) {
    __shared__ unsigned short Xs[64][40];
    __shared__ unsigned short Ns[64][40];
    int tid = threadIdx.x;
    int m0 = blockIdx.y * 64, n0 = blockIdx.x * 64;
    int r = tid >> 2, p = (tid & 3) * 8;
    const unsigned short* xg = j.X + (size_t)(m0 + r) * j.ldx + p;
    const unsigned short* wg = j.WT + (size_t)(n0 + r) * j.K + p;
    int lane = tid & 63, wv = tid >> 6;
    int wm = (wv & 1) * 32, wn = (wv >> 1) * 32;
    int mi = lane & 15, q = lane >> 4;
    floatx4 acc00 = {0.f, 0.f, 0.f, 0.f};
    floatx4 acc01 = acc00, acc10 = acc00, acc11 = acc00;
    for (int kt = 0; kt < j.K; kt += 32) {
        *(float4*)&Xs[r][p] = *(const float4*)(xg + kt);
        *(float4*)&Ns[r][p] = *(const float4*)(wg + kt);
        __syncthreads();
        s16x8 a0 = *(const s16x8*)&Xs[wm + mi][q * 8];
        s16x8 a1 = *(const s16x8*)&Xs[wm + 16 + mi][q * 8];
        s16x8 b0 = *(const s16x8*)&Ns[wn + mi][q * 8];
        s16x8 b1 = *(const s16x8*)&Ns[wn + 16 + mi][q * 8];
        acc00 = __builtin_amdgcn_mfma_f32_16x16x32_bf16(a0, b0, acc00, 0, 0, 0);
        acc01 = __builtin_amdgcn_mfma_f32_16x16x32_bf16(a0, b1, acc01, 0, 0, 0);
        acc10 = __builtin_amdgcn_mfma_f32_16x16x32_bf16(a1, b0, acc10, 0, 0, 0);
        acc11 = __builtin_amdgcn_mfma_f32_16x16x32_bf16(a1, b1, acc11, 0, 0, 0);
        __syncthreads();
    }
    #pragma unroll
    for (int i = 0; i < 2; ++i) {
        #pragma unroll
        for (int jj = 0; jj < 2; ++jj) {
            floatx4 a = (i == 0) ? ((jj == 0) ? acc00 : acc01)
                                 : ((jj == 0) ? acc10 : acc11);
            int col = n0 + wn + jj * 16 + mi;
            float badd = j.bias ? j.bias[col] : 0.f;
            #pragma unroll
            for (int rg = 0; rg < 4; ++rg) {
                int row = m0 + wm + i * 16 + q * 4 + rg;
                float v = a[rg] + badd;
                if (j.flags & 4) v += bf2f(j.addb[(size_t)row * j.N + col]);
                if (j.flags & 1) v = elu1(v);
                if (j.flags & 2)
                    ((unsigned short*)j.out)[(size_t)row * j.ldo + col] = f2bf(v);
                else
                    ((float*)j.out)[(size_t)row * j.ldo + col] = v;
            }
        }
    }
}

// ---------------------------------------------------------------- scan tile GEMM
// C[32,128] = A(LDS [32][1032]) @ WT[n0..n0+128][1024]^T ; wave wv owns cols wv*32..+32
__device__ __forceinline__ void gemm_tile(const unsigned short (*As)[1032],
                                          const unsigned short* __restrict__ WTn0,
                                          int lane, int wv, floatx4 acc[2][2]) {
    int mi = lane & 15, q = lane >> 4;
    const unsigned short* bg0 = WTn0 + (size_t)(wv * 32 + mi) * 1024 + q * 8;
    const unsigned short* bg1 = bg0 + 16 * 1024;
    float4 pb0[4], pb1[4];
    #pragma unroll
    for (int i = 0; i < 4; ++i) {
        pb0[i] = *(const float4*)(bg0 + i * 32);
        pb1[i] = *(const float4*)(bg1 + i * 32);
    }
    #pragma unroll
    for (int kk = 0; kk < 32; ++kk) {
        union { float4 f; s16x8 s; } b0, b1;
        b0.f = pb0[kk & 3]; b1.f = pb1[kk & 3];
        if (kk < 28) {
            pb0[kk & 3] = *(const float4*)(bg0 + (kk + 4) * 32);
            pb1[kk & 3] = *(const float4*)(bg1 + (kk + 4) * 32);
        }
        s16x8 a0 = *(const s16x8*)&As[mi][kk * 32 + q * 8];
        s16x8 a1 = *(const s16x8*)&As[16 + mi][kk * 32 + q * 8];
        acc[0][0] = __builtin_amdgcn_mfma_f32_16x16x32_bf16(a0, b0.s, acc[0][0], 0, 0, 0);
        acc[0][1] = __builtin_amdgcn_mfma_f32_16x16x32_bf16(a0, b1.s, acc[0][1], 0, 0, 0);
        acc[1][0] = __builtin_amdgcn_mfma_f32_16x16x32_bf16(a1, b0.s, acc[1][0], 0, 0, 0);
        acc[1][1] = __builtin_amdgcn_mfma_f32_16x16x32_bf16(a1, b1.s, acc[1][1], 0, 0, 0);
    }
}

__device__ __forceinline__ void loadA(unsigned short (*As)[1032],
                                      const unsigned short* __restrict__ src,
                                      int ldsrc, int tid) {
    #pragma unroll
    for (int i = 0; i < 16; ++i) {
        int e = (i * 256 + tid) * 8;
        int rowi = e >> 10, col = e & 1023;
        *(float4*)&As[rowi][col] = *(const float4*)(src + (size_t)rowi * ldsrc + col);
    }
}

// ---------------------------------------------------------------- persistent XCD-group scan
struct ScanP {
    const unsigned short *WhT, *Wq1aT, *Wq2T, *WizBF, *Eq;
    const float *Wi, *bi, *bh, *bq2, *gum;
    const int *act_idx;
    unsigned short *XZ, *post1c, *postL;
    float *ghbuf, *h_st;
    int *zidx;
    int *bar;
};

__global__ __launch_bounds__(256, 1) void k_scan(ScanP P) {
    __shared__ unsigned short As[48][1032];   // 99 KB -> forces 1 block/CU
    __shared__ int zsh[34];
    __shared__ int sh_rank, sh_xcc, sh_cnt[8];
    int tid = threadIdx.x;
    int lane = tid & 63, wv = tid >> 6;
    int mi = lane & 15, q = lane >> 4;
    int* bar = P.bar;

    // ---- census: group = physical XCD
    if (tid == 0) {
        int xcc;
        asm volatile("s_getreg_b32 %0, hwreg(HW_REG_XCC_ID)" : "=s"(xcc));
        xcc &= 7;
        sh_xcc = xcc;
        sh_rank = atomicAdd(&bar[CNT_OFF + xcc], 1);
    }
    __syncthreads();
    int grp = sh_xcc, rank = sh_rank;

    // ---- one-time global entry barrier (cross-XCD; relaxed atomics)
    rel_drain();
    __syncthreads();
    if (tid == 0)
        __hip_atomic_store(&bar[GARR_OFF + blockIdx.x * 16], 1,
                           __ATOMIC_RELAXED, __HIP_MEMORY_SCOPE_AGENT);
    if (blockIdx.x == 0) {
        while (__hip_atomic_load(&bar[GARR_OFF + tid * 16],
                                 __ATOMIC_RELAXED, __HIP_MEMORY_SCOPE_AGENT) < 1)
            __builtin_amdgcn_s_sleep(2);
        __syncthreads();
        if (tid == 0)
            __hip_atomic_store(&bar[GGO_OFF], 1, __ATOMIC_RELAXED, __HIP_MEMORY_SCOPE_AGENT);
    } else if (tid == 0) {
        while (__hip_atomic_load(&bar[GGO_OFF],
                                 __ATOMIC_RELAXED, __HIP_MEMORY_SCOPE_AGENT) < 1)
            __builtin_amdgcn_s_sleep(2);
    }
    __syncthreads();
    acq_fence();

    if (tid < 8)
        sh_cnt[tid] = __hip_atomic_load(&bar[CNT_OFF + tid],
                                        __ATOMIC_RELAXED, __HIP_MEMORY_SCOPE_AGENT);
    __syncthreads();
    int nb = sh_cnt[grp];
    int kg = 0, jg = 0;
    #pragma unroll
    for (int g = 0; g < 8; ++g) {
        if (sh_cnt[g] > 0) { if (g == grp) jg = kg; ++kg; }
    }
    int mych[8], nchunk = 0;
    for (int c = jg; c < 8; c += kg) mych[nchunk++] = c;

    int ep = 0;
    for (int t = 1; t <= TT; ++t) {
        // ---------- S_A: GRU + z-gather (1 row / block)
        for (int ci = 0; ci < nchunk; ++ci) {
            int c = mych[ci];
            for (int r = rank; r < 32; r += nb) {
                int grow = c * 32 + r;
                __syncthreads();
                if (tid < 32) zsh[tid] = (t > 1) ? (tid * 32 + P.zidx[grow * 32 + tid]) : 0;
                if (tid == 0) zsh[32] = 1024 + P.act_idx[(t - 1) * 256 + grow];
                __syncthreads();
                int j0 = tid * 4;
                float g[3][4];
                #pragma unroll
                for (int gi = 0; gi < 3; ++gi) {
                    int col = gi * 1024 + j0;
                    float4 bi4 = *(const float4*)(P.bi + col);
                    float4 wa  = *(const float4*)(P.Wi + (size_t)zsh[32] * G3 + col);
                    g[gi][0] = bi4.x + wa.x; g[gi][1] = bi4.y + wa.y;
                    g[gi][2] = bi4.z + wa.z; g[gi][3] = bi4.w + wa.w;
                }
                if (t > 1) {
                    #pragma unroll 4
                    for (int cc = 0; cc < 32; ++cc) {
                        const unsigned short* wr = P.WizBF + (size_t)zsh[cc] * G3 + j0;
                        #pragma unroll
                        for (int gi = 0; gi < 3; ++gi) {
                            u64 w = *(const u64*)(wr + gi * 1024);
                            g[gi][0] += bf2f((unsigned short)w);
                            g[gi][1] += bf2f((unsigned short)(w >> 16));
                            g[gi][2] += bf2f((unsigned short)(w >> 32));
                            g[gi][3] += bf2f((unsigned short)(w >> 48));
                        }
                    }
                }
                const float* ghs = (t == 1) ? P.bh : (P.ghbuf + (size_t)grow * G3);
                float4 gr = *(const float4*)(ghs + j0);
                float4 gu = *(const float4*)(ghs + 1024 + j0);
                float4 gn = *(const float4*)(ghs + 2048 + j0);
                float4 hp = *(const float4*)(P.h_st + (size_t)grow * HID + j0);
                float grv[4] = {gr.x, gr.y, gr.z, gr.w};
                float guv[4] = {gu.x, gu.y, gu.z, gu.w};
                float gnv[4] = {gn.x, gn.y, gn.z, gn.w};
                float hpv[4] = {hp.x, hp.y, hp.z, hp.w};
                float ho[4];
                #pragma unroll
                for (int kq = 0; kq < 4; ++kq) {
                    float rr = sigm(g[0][kq] + grv[kq]);
                    float uu = sigm(g[1][kq] + guv[kq]);
                    float nn = tanhf(g[2][kq] + rr * gnv[kq]);
                    ho[kq] = (1.f - uu) * nn + uu * hpv[kq];
                }
                *(float4*)(P.h_st + (size_t)grow * HID + j0) =
                    make_float4(ho[0], ho[1], ho[2], ho[3]);
                u64 pk = (u64)f2bf(ho[0]) | ((u64)f2bf(ho[1]) << 16) |
                         ((u64)f2bf(ho[2]) << 32) | ((u64)f2bf(ho[3]) << 48);
                *(u64*)(P.XZ + ((size_t)t * 256 + grow) * 2048 + j0) = pk;
            }
        }
        gbar(bar, grp, rank, nb, ++ep);

        // ---------- S_B: gh_{t+1} (jobs 0..23) | post1_t (jobs 24..31)
        for (int ci = 0; ci < nchunk; ++ci) {
            int c = mych[ci];
            __syncthreads();
            loadA(As, P.XZ + ((size_t)t * 256 + c * 32) * 2048, 2048, tid);
            __syncthreads();
            for (int job = rank; job < 32; job += nb) {
                if (job < 24) {
                    if (t == TT) continue;
                    int n0 = job * 128;
                    floatx4 z4 = {0.f, 0.f, 0.f, 0.f};
                    floatx4 acc[2][2] = {{z4, z4}, {z4, z4}};
                    gemm_tile(As, P.WhT + (size_t)n0 * 1024, lane, wv, acc);
                    #pragma unroll
                    for (int mt = 0; mt < 2; ++mt)
                        #pragma unroll
                        for (int jj = 0; jj < 2; ++jj) {
                            int col = n0 + wv * 32 + jj * 16 + mi;
                            float bb = P.bh[col];
                            #pragma unroll
                            for (int rg = 0; rg < 4; ++rg) {
                                int grow = c * 32 + mt * 16 + q * 4 + rg;
                                P.ghbuf[(size_t)grow * G3 + col] = acc[mt][jj][rg] + bb;
                            }
                        }
                } else {
                    int n0 = (job - 24) * 128;
                    floatx4 z4 = {0.f, 0.f, 0.f, 0.f};
                    floatx4 acc[2][2] = {{z4, z4}, {z4, z4}};
                    gemm_tile(As, P.Wq1aT + (size_t)n0 * 1024, lane, wv, acc);
                    #pragma unroll
                    for (int mt = 0; mt < 2; ++mt)
                        #pragma unroll
                        for (int jj = 0; jj < 2; ++jj) {
                            int col = n0 + wv * 32 + jj * 16 + mi;
                            #pragma unroll
                            for (int rg = 0; rg < 4; ++rg) {
                                int lr = mt * 16 + q * 4 + rg;
                                int grow = c * 32 + lr;
                                unsigned short eb = __builtin_nontemporal_load(
                                    P.Eq + ((size_t)(t - 1) * 256 + grow) * 1024 + col);
                                float v = elu1(acc[mt][jj][rg] + bf2f(eb));
                                P.post1c[(size_t)c * 32768 + lr * 1024 + col] = f2bf(v);
                            }
                        }
                }
            }
        }
        gbar(bar, grp, rank, nb, ++ep);

        // ---------- S_C: postL_t + gumbel sample (jobs 0..7)
        for (int ci = 0; ci < nchunk; ++ci) {
            int c = mych[ci];
            __syncthreads();
            if (rank < 8) loadA(As, P.post1c + (size_t)c * 32768, 1024, tid);
            __syncthreads();
            for (int job = rank; job < 8; job += nb) {
                int n0 = job * 128;
                floatx4 z4 = {0.f, 0.f, 0.f, 0.f};
                floatx4 acc[2][2] = {{z4, z4}, {z4, z4}};
                gemm_tile(As, P.Wq2T + (size_t)n0 * 1024, lane, wv, acc);
                // bias + store postL (nt)
                #pragma unroll
                for (int mt = 0; mt < 2; ++mt)
                    #pragma unroll
                    for (int jj = 0; jj < 2; ++jj) {
                        int col = n0 + wv * 32 + jj * 16 + mi;
                        float bb = P.bq2[col];
                        #pragma unroll
                        for (int rg = 0; rg < 4; ++rg) {
                            acc[mt][jj][rg] += bb;
                            int grow = c * 32 + mt * 16 + q * 4 + rg;
                            __builtin_nontemporal_store(f2bf(acc[mt][jj][rg]),
                                P.postL + ((size_t)(t - 1) * 256 + grow) * 1024 + col);
                        }
                    }
                // gumbel-argmax: wave's 32 cols = one category
                int cat = (n0 >> 5) + wv;
                #pragma unroll
                for (int mt = 0; mt < 2; ++mt) {
                    #pragma unroll
                    for (int rg = 0; rg < 4; ++rg) {
                        int grow = c * 32 + mt * 16 + q * 4 + rg;
                        const float* gr = P.gum + ((size_t)(t - 1) * 256 + grow) * 1024 + cat * 32;
                        float v0 = acc[mt][0][rg] + __builtin_nontemporal_load(gr + mi);
                        float v1 = acc[mt][1][rg] + __builtin_nontemporal_load(gr + 16 + mi);
                        float bv; int cls;
                        if (v1 > v0) { bv = v1; cls = 16 + mi; } else { bv = v0; cls = mi; }
                        #pragma unroll
                        for (int off = 1; off < 16; off <<= 1) {
                            float ov = __shfl_xor(bv, off);
                            int oc = __shfl_xor(cls, off);
                            if (ov > bv || (ov == bv && oc < cls)) { bv = ov; cls = oc; }
                        }
                        unsigned short* zo = P.XZ + ((size_t)t * 256 + grow) * 2048 + 1024 + cat * 32;
                        zo[mi] = (mi == cls) ? 0x3F80 : 0;
                        zo[16 + mi] = (16 + mi == cls) ? 0x3F80 : 0;
                        if (mi == 0) P.zidx[grow * 32 + cat] = cls;
                    }
                }
            }
        }
        gbar(bar, grp, rank, nb, ++ep);
    }
}

// ---------------------------------------------------------------- KL (deferred)
__global__ void k_kl(const unsigned short* __restrict__ postL,
                     const unsigned short* __restrict__ priorL,
                     float* __restrict__ kl_acc) {
    int g = blockIdx.x * 256 + threadIdx.x;
    int sidx = g >> 5, cat = g & 31;
    const unsigned short* ql = postL + (size_t)sidx * ZD + cat * NCLS;
    const unsigned short* pl = priorL + (size_t)sidx * ZD + cat * NCLS;
    float vq[32], vp[32];
    float mq = -1e30f, mp = -1e30f;
    #pragma unroll
    for (int i = 0; i < NCLS; ++i) {
        vq[i] = bf2f(ql[i]); vp[i] = bf2f(pl[i]);
        mq = fmaxf(mq, vq[i]); mp = fmaxf(mp, vp[i]);
    }
    float sq = 0.f, sp = 0.f;
    #pragma unroll
    for (int i = 0; i < NCLS; ++i) { sq += expf(vq[i] - mq); sp += expf(vp[i] - mp); }
    float lseq = mq + logf(sq), lsep = mp + logf(sp);
    float kl = 0.f;
    #pragma unroll
    for (int i = 0; i < NCLS; ++i) {
        float lpq = vq[i] - lseq;
        kl += expf(lpq) * (lpq - (vp[i] - lsep));
    }
    __shared__ float red[256];
    red[threadIdx.x] = kl;
    __syncthreads();
    for (int s = 128; s > 0; s >>= 1) {
        if ((int)threadIdx.x < s) red[threadIdx.x] += red[threadIdx.x + s];
        __syncthreads();
    }
    if (threadIdx.x == 0) atomicAdd(&kl_acc[sidx >> 8], red[0]);
}

// ---------------------------------------------------------------- CE over 512 logits
__global__ void k_ce(const unsigned short* __restrict__ logits,
                     const int* __restrict__ obs_idx, float* __restrict__ ce_acc) {
    int s = (blockIdx.x * 256 + threadIdx.x) >> 6;
    int lane = threadIdx.x & 63;
    union { float4 f4; unsigned short u[8]; } raw;
    raw.f4 = *(const float4*)(logits + (size_t)s * OBS + lane * 8);
    float v[8];
    float m = -1e30f;
    #pragma unroll
    for (int i = 0; i < 8; ++i) { v[i] = bf2f(raw.u[i]); m = fmaxf(m, v[i]); }
    #pragma unroll
    for (int off = 32; off > 0; off >>= 1) m = fmaxf(m, __shfl_xor(m, off));
    float sum = 0.f;
    #pragma unroll
    for (int i = 0; i < 8; ++i) sum += expf(v[i] - m);
    #pragma unroll
    for (int off = 32; off > 0; off >>= 1) sum += __shfl_xor(sum, off);
    float lse = m + logf(sum);
    int tgt = obs_idx[s];
    float tv = 0.f;
    #pragma unroll
    for (int i = 0; i < 8; ++i) if (lane * 8 + i == tgt) tv = v[i];
    #pragma unroll
    for (int off = 32; off > 0; off >>= 1) tv += __shfl_xor(tv, off);
    if (lane == 0) atomicAdd(&ce_acc[s >> 8], lse - tv);
}

// ---------------------------------------------------------------- reward / continue heads
__global__ void k_heads(const unsigned short* __restrict__ dec1,
                        const float* __restrict__ Wr2, const float* __restrict__ br2,
                        const float* __restrict__ Wc2, const float* __restrict__ bc2,
                        const float* __restrict__ rew, const float* __restrict__ done,
                        float* __restrict__ mse_acc, float* __restrict__ bce_acc) {
    int s = (blockIdx.x * 256 + threadIdx.x) >> 6;
    int lane = threadIdx.x & 63;
    float vr = bf2f(dec1[(size_t)s * 192 + 64 + lane]) * Wr2[lane];
    float vc = bf2f(dec1[(size_t)s * 192 + 128 + lane]) * Wc2[lane];
    #pragma unroll
    for (int off = 32; off > 0; off >>= 1) {
        vr += __shfl_xor(vr, off);
        vc += __shfl_xor(vc, off);
    }
    if (lane == 0) {
        float r_pred = vr + br2[0], c_pred = vc + bc2[0];
        float rt = rew[s];
        float sgn = (rt > 0.f) ? 1.f : ((rt < 0.f) ? -1.f : 0.f);
        float r_tgt = sgn * log1pf(fabsf(rt));
        float d = r_pred - r_tgt;
        float ct = 1.f - done[s];
        float bce = fmaxf(c_pred, 0.f) - c_pred * ct + log1pf(expf(-fabsf(c_pred)));
        atomicAdd(&mse_acc[s >> 8], d * d);
        atomicAdd(&bce_acc[s >> 8], bce);
    }
}

// ---------------------------------------------------------------- final reduce
__global__ void k_final(const float* __restrict__ ce_acc, const float* __restrict__ mse_acc,
                        const float* __restrict__ bce_acc, const float* __restrict__ kl_acc,
                        float* __restrict__ out) {
    int t = threadIdx.x;
    float ce = ce_acc[t] * (1.f / 256.f);
    float ms = mse_acc[t] * (1.f / 256.f);
    float bc = bce_acc[t] * (1.f / 256.f);
    float ka = kl_acc[t] * (1.f / 256.f);
    float kt = fmaxf(ka, 1.f);
    #pragma unroll
    for (int off = 32; off > 0; off >>= 1) {
        ce += __shfl_down(ce, off);
        ms += __shfl_down(ms, off);
        bc += __shfl_down(bc, off);
        kt += __shfl_down(kt, off);
    }
    if (t == 0) {
        ce *= (1.f / 64.f); ms *= (1.f / 64.f); bc *= (1.f / 64.f); kt *= (1.f / 64.f);
        out[0] = ce + ms + bc + kt;
        out[1] = ce; out[2] = ms; out[3] = bc; out[4] = kt;
    }
}

// ----------------------------------------------------------------------------------
extern "C" void kernel_launch(void* const* d_in, const int* in_sizes, int n_in,
                              void* d_out, int out_size, void* d_ws, size_t ws_size,
                              hipStream_t stream) {
    const float* obs  = (const float*)d_in[0];
    const float* act  = (const float*)d_in[1];
    const float* rew  = (const float*)d_in[2];
    const float* done = (const float*)d_in[3];
    const float* gum  = (const float*)d_in[4];
    const float* We1  = (const float*)d_in[5];
    const float* be1  = (const float*)d_in[6];
    const float* We2  = (const float*)d_in[7];
    const float* be2  = (const float*)d_in[8];
    const float* Wi   = (const float*)d_in[9];
    const float* Wh   = (const float*)d_in[10];
    const float* bi   = (const float*)d_in[11];
    const float* bh   = (const float*)d_in[12];
    const float* Wp1  = (const float*)d_in[13];
    const float* bp1  = (const float*)d_in[14];
    const float* Wp2  = (const float*)d_in[15];
    const float* bp2  = (const float*)d_in[16];
    const float* Wq1  = (const float*)d_in[17];
    const float* bq1  = (const float*)d_in[18];
    const float* Wq2  = (const float*)d_in[19];
    const float* bq2  = (const float*)d_in[20];
    const float* Wd1  = (const float*)d_in[21];
    const float* bd1  = (const float*)d_in[22];
    const float* Wd2  = (const float*)d_in[23];
    const float* bd2  = (const float*)d_in[24];
    const float* Wr1  = (const float*)d_in[25];
    const float* br1  = (const float*)d_in[26];
    const float* Wr2  = (const float*)d_in[27];
    const float* br2  = (const float*)d_in[28];
    const float* Wc1  = (const float*)d_in[29];
    const float* bc1  = (const float*)d_in[30];
    const float* Wc2  = (const float*)d_in[31];
    const float* bc2  = (const float*)d_in[32];

    char* base = (char*)d_ws;
    size_t off = 0;
    auto alloc = [&](size_t bytes) -> char* {
        char* p = base + off;
        off += (bytes + 255) & ~(size_t)255;
        return p;
    };
    unsigned short* WhT   = (unsigned short*)alloc(3072u * 1024 * 2);
    unsigned short* WizBF = (unsigned short*)alloc(1024u * 3072 * 2);
    unsigned short* Wq1aT = (unsigned short*)alloc(1024u * 1024 * 2);
    unsigned short* Wq1bT = (unsigned short*)alloc(1024u * 512 * 2);
    unsigned short* Wq2T  = (unsigned short*)alloc(1024u * 1024 * 2);
    unsigned short* Wp1T  = (unsigned short*)alloc(1024u * 1024 * 2);
    unsigned short* Wp2T  = (unsigned short*)alloc(1024u * 1024 * 2);
    unsigned short* WdrcT = (unsigned short*)alloc(192u * 2048 * 2);
    unsigned short* Wd2T  = (unsigned short*)alloc(512u * 64 * 2);
    unsigned short* We2T  = (unsigned short*)alloc(512u * 64 * 2);
    float*          b_drc = (float*)alloc(192 * 4);
    unsigned short* XZ    = (unsigned short*)alloc(65u * 256 * 2048 * 2);   // 68 MB
    float*          h_st  = (float*)alloc(256u * 1024 * 4);
    float*          ghbuf = (float*)alloc(256u * 3072 * 4);
    unsigned short* post1c= (unsigned short*)alloc(8u * 32 * 1024 * 2);
    unsigned short* postL = (unsigned short*)alloc(16384u * 1024 * 2);      // 32 MB (reused: logits)
    unsigned short* Eq    = (unsigned short*)alloc(16384u * 1024 * 2);      // 32 MB (reused: priorL)
    unsigned short* pri1  = (unsigned short*)alloc(16384u * 1024 * 2);      // 32 MB
    unsigned short* dec1  = (unsigned short*)alloc(16384u * 192 * 2);
    float*          acc   = (float*)alloc(256 * 4);
    int*            obs_idx = (int*)alloc(16384 * 4);
    int*            act_idx = (int*)alloc(16384 * 4);
    int*            zidx    = (int*)alloc(256 * 32 * 4);
    int*            bar     = (int*)alloc(BAR_INTS * 4);
    unsigned short* embed = pri1;                    // setup-time aliases (pri1 unused then)
    unsigned short* e1    = pri1 + 16384u * 512;

    hipMemsetAsync(h_st, 0, 256u * 1024 * 4, stream);
    hipMemsetAsync(acc, 0, 256 * 4, stream);
    hipMemsetAsync(bar, 0, BAR_INTS * 4, stream);

    k_idx<<<4096, 256, 0, stream>>>(obs, act, obs_idx, act_idx);

    dim3 tb(32, 8);
    k_transp<<<dim3(96, 32), tb, 0, stream>>>(Wh, 3072, WhT, 1024, 0);
    k_cast<<<(1024 * 3072) / 256, 256, 0, stream>>>(Wi, WizBF, 1024 * 3072);
    k_transp<<<dim3(32, 32), tb, 0, stream>>>(Wq1, 1024, Wq1aT, 1024, 0);
    k_transp<<<dim3(32, 16), tb, 0, stream>>>(Wq1 + 1024u * 1024, 1024, Wq1bT, 512, 0);
    k_transp<<<dim3(32, 32), tb, 0, stream>>>(Wq2, 1024, Wq2T, 1024, 0);
    k_transp<<<dim3(32, 32), tb, 0, stream>>>(Wp1, 1024, Wp1T, 1024, 0);
    k_transp<<<dim3(32, 32), tb, 0, stream>>>(Wp2, 1024, Wp2T, 1024, 0);
    k_transp<<<dim3(2, 64),  tb, 0, stream>>>(Wd1, 64, WdrcT, 2048, 0);
    k_transp<<<dim3(2, 64),  tb, 0, stream>>>(Wr1, 64, WdrcT + 64u * 2048, 2048, 0);
    k_transp<<<dim3(2, 64),  tb, 0, stream>>>(Wc1, 64, WdrcT + 128u * 2048, 2048, 0);
    k_transp<<<dim3(16, 2),  tb, 0, stream>>>(Wd2, 512, Wd2T, 64, 0);
    k_transp<<<dim3(16, 2),  tb, 0, stream>>>(We2, 512, We2T, 64, 0);
    k_pack_bias<<<1, 192, 0, stream>>>(bd1, br1, bc1, b_drc);

    // embed & Eq precompute (all 64 steps)
    k_e1<<<4096, 256, 0, stream>>>(obs_idx, We1, be1, e1);
    {
        MJob m = { e1, 64, We2T, be2, nullptr, embed, 512, 512, 64, 2 };
        mfma_gemm<<<dim3(8, 256), 256, 0, stream>>>(m);
    }
    {
        MJob m = { embed, 512, Wq1bT, bq1, nullptr, Eq, 1024, 1024, 512, 2 };
        mfma_gemm<<<dim3(16, 256), 256, 0, stream>>>(m);
    }

    // persistent XCD-group scan (cooperative launch for co-residency)
    ScanP SP;
    SP.WhT = WhT; SP.Wq1aT = Wq1aT; SP.Wq2T = Wq2T; SP.WizBF = WizBF; SP.Eq = Eq;
    SP.Wi = Wi; SP.bi = bi; SP.bh = bh; SP.bq2 = bq2; SP.gum = gum;
    SP.act_idx = act_idx;
    SP.XZ = XZ; SP.post1c = post1c; SP.postL = postL;
    SP.ghbuf = ghbuf; SP.h_st = h_st; SP.zidx = zidx; SP.bar = bar;
    void* kargs[] = { (void*)&SP };
    hipLaunchCooperativeKernel((const void*)k_scan, dim3(256), dim3(256), kargs, 0, stream);

    // deferred batched passes
    unsigned short* Hall = XZ + (size_t)256 * 2048;
    {   // prior1 = elu(H @ Wp1 + bp1)
        MJob m = { Hall, 2048, Wp1T, bp1, nullptr, pri1, 1024, 1024, 1024, 1 | 2 };
        mfma_gemm<<<dim3(16, 256), 256, 0, stream>>>(m);
    }
    {   // priorL = prior1 @ Wp2 + bp2 (into Eq buffer)
        MJob m = { pri1, 1024, Wp2T, bp2, nullptr, Eq, 1024, 1024, 1024, 2 };
        mfma_gemm<<<dim3(16, 256), 256, 0, stream>>>(m);
    }
    k_kl<<<2048, 256, 0, stream>>>(postL, Eq, acc + 192);
    {
        MJob m = { Hall, 2048, WdrcT, b_drc, nullptr, dec1, 192, 192, 2048, 1 | 2 };
        mfma_gemm<<<dim3(3, 256), 256, 0, stream>>>(m);
    }
    {
        MJob m = { dec1, 192, Wd2T, bd2, nullptr, postL, 512, 512, 64, 2 };
        mfma_gemm<<<dim3(8, 256), 256, 0, stream>>>(m);
    }
    k_ce<<<4096, 256, 0, stream>>>(postL, obs_idx, acc + 0);
    k_heads<<<4096, 256, 0, stream>>>(dec1, Wr2, br2, Wc2, bc2, rew, done,
                                      acc + 64, acc + 128);
    k_final<<<1, 64, 0, stream>>>(acc + 0, acc + 64, acc + 128, acc + 192, (float*)d_out);
}